// Round 7
// baseline (4674.806 us; speedup 1.0000x reference)
//
#include <hip/hip_runtime.h>
#include <hip/hip_bf16.h>
#include <math.h>

#define B_ 128
#define T_ 256
#define F_ 64
#define H_ 512
#define G4_ 2048

// dynamic LDS layout (bytes)
#define WH_OFF 0        // 4 waves x 16KB Wh fragments
#define WX_OFF 65536    // 4 waves x 16KB Wx fragments
#define G_OFF  131072   // float g[4][32][17] = 8704B
#define SMEM_TOTAL 139776

typedef __attribute__((ext_vector_type(8))) short bf16x8;
typedef __attribute__((ext_vector_type(4))) float f32x4;

__device__ __forceinline__ float sigmoidf_(float x) { return 1.f / (1.f + expf(-x)); }

__device__ __forceinline__ void coh_store_u32(unsigned* p, unsigned v) {
  __hip_atomic_store(p, v, __ATOMIC_RELAXED, __HIP_MEMORY_SCOPE_AGENT);
}
__device__ __forceinline__ unsigned coh_load_u32(const unsigned* p) {
  return __hip_atomic_load(p, __ATOMIC_RELAXED, __HIP_MEMORY_SCOPE_AGENT);
}

// Domain barrier over 64 blocks (one batch-strip's grp0+grp1 blocks).
// All-poll-all flags + agent acquire-fence (L1/L2 invalidate) so subsequent
// PLAIN loads refetch fresh data. Weights are LDS-resident, so the invalidate
// does not trigger a weight refetch (round-2 failure mode).
__device__ __forceinline__ void dom_barrier(unsigned* dflags, int idx, int tid,
                                            unsigned s1) {
  asm volatile("s_waitcnt vmcnt(0)" ::: "memory");  // data stores at IF
  __syncthreads();                                  // whole block drained
  if (tid == 0) coh_store_u32(&dflags[idx], s1);
  if (tid < 64) {
    while (coh_load_u32(&dflags[tid]) < s1) __builtin_amdgcn_s_sleep(8);
  }
  __syncthreads();
  __builtin_amdgcn_fence(__ATOMIC_ACQUIRE, "agent");  // invalidate L1/L2
}

// ---- transpose+cast four [512,2048] fp32 weight mats -> [2048,512] bf16 ----
__global__ __launch_bounds__(256) void transpose_cast_k(
    const float* __restrict__ s0, const float* __restrict__ s1,
    const float* __restrict__ s2, const float* __restrict__ s3,
    __hip_bfloat16* __restrict__ dst)
{
  __shared__ float lds[64][65];
  const float* src = (blockIdx.z == 0) ? s0 : (blockIdx.z == 1) ? s1 : (blockIdx.z == 2) ? s2 : s3;
  __hip_bfloat16* d = dst + (size_t)blockIdx.z * (G4_ * H_);
  int n0 = blockIdx.x * 64, k0 = blockIdx.y * 64;
  int tx = threadIdx.x & 63, ty = threadIdx.x >> 6;
#pragma unroll
  for (int r = 0; r < 16; r++) { int k = r * 4 + ty; lds[k][tx] = src[(size_t)(k0 + k) * G4_ + n0 + tx]; }
  __syncthreads();
#pragma unroll
  for (int r = 0; r < 16; r++) { int n = r * 4 + ty; d[(size_t)(n0 + n) * H_ + k0 + tx] = __float2bfloat16(lds[tx][n]); }
}

// ---- cast W1 to bf16 + zero state buffers & barrier flags ----
__global__ void prep_misc_k(const float* __restrict__ w1, __hip_bfloat16* __restrict__ w1b,
                            float* __restrict__ zbase, int nzero)
{
  int i = blockIdx.x * blockDim.x + threadIdx.x;
  int stride = gridDim.x * blockDim.x;
  for (int k = i; k < F_ * H_; k += stride) w1b[k] = __float2bfloat16(w1[k]);
  for (int k = i; k < nzero; k += stride) zbase[k] = 0.f;
}

// ---- dense1 + spectral-norm row normalization; h0 out as bf16 [B*T, H] ----
__global__ __launch_bounds__(512) void dense1_k(
    const float* __restrict__ x, const __hip_bfloat16* __restrict__ w1b,
    const float* __restrict__ b1, __hip_bfloat16* __restrict__ h0)
{
  __shared__ float red[8];
  int j = threadIdx.x;
  int wave = j >> 6, lane = j & 63;
  float wcol[64];
#pragma unroll
  for (int k = 0; k < 64; k++) wcol[k] = __bfloat162float(w1b[k * H_ + j]);
  float bj = b1[j];
  for (int r = 0; r < 32; r++) {
    int row = blockIdx.x * 32 + r;
    const float* xr = x + (size_t)row * F_;
    float acc = bj;
#pragma unroll
    for (int k = 0; k < 64; k++) acc += xr[k] * wcol[k];
    float ss = acc * acc;
#pragma unroll
    for (int o = 32; o; o >>= 1) ss += __shfl_down(ss, o);
    if (lane == 0) red[wave] = ss;
    __syncthreads();
    float tot = red[0] + red[1] + red[2] + red[3] + red[4] + red[5] + red[6] + red[7];
    float sc = sqrtf(512.f) / fmaxf(sqrtf(tot), 1e-12f);
    h0[(size_t)row * H_ + j] = __float2bfloat16(acc * sc);
    __syncthreads();
  }
}

// ---- fused persistent LSTM1+LSTM2, diagonally pipelined, weights in LDS ----
// 256 blocks (1/CU): grp0 = blocks 0..127 run LSTM1 step s; grp1 = 128..255
// run LSTM2 step s-1. Per grp: 4 batch-strips(32) x 32 unit-strips(16).
// Wave w = gate w over a 32(batch)x16(unit) tile, K=1024 (h@Wh + x@Wx).
// Round 7: __launch_bounds__(256,1). r5/r6 both ran at VGPR_Count=40 (the
// compiler allocated for 8-wave occupancy that LDS already forbids), so only
// ~2-4 of the 64 A-fragment loads could be in flight -> K-loops serialized
// into ~10 x 900-cycle IF-latency chains = the measured 17us/step. With 1
// wave/SIMD declared (~512 VGPR budget) we burst-load ALL 64 A-fragments
// into registers, then MFMA from registers + LDS weights: exposed latency
// ~= one IF round-trip per step.
__global__ __launch_bounds__(256, 1) void lstm_fused_k(
    const __hip_bfloat16* __restrict__ h0,     // [B*T, H] dense1 output (LSTM1 x)
    __hip_bfloat16* __restrict__ seq,          // [B*T, H] LSTM1 out / LSTM2 x
    const __hip_bfloat16* __restrict__ wh1, const __hip_bfloat16* __restrict__ wx1,
    const float* __restrict__ bl1,
    const __hip_bfloat16* __restrict__ wh2, const __hip_bfloat16* __restrict__ wx2,
    const float* __restrict__ bl2,
    __hip_bfloat16* __restrict__ h1A, __hip_bfloat16* __restrict__ h1B,
    __hip_bfloat16* __restrict__ h2A, __hip_bfloat16* __restrict__ h2B,
    float* __restrict__ h2f,                   // [B, H] fp32 final h of LSTM2
    unsigned* flags)                           // 4 domains x 64 flags
{
  extern __shared__ char smem[];
  const int tid = threadIdx.x;
  const int wave = tid >> 6;
  const int lane = tid & 63;
  const int lr = lane & 15;   // m (A-rows) / n (B-cols) within 16-tile
  const int lk = lane >> 4;   // k-octet quad
  const int bid = blockIdx.x;
  const int grp = bid >> 7;
  const int lid = bid & 127;
  const int bb = lid & 3;     // batch strip (32 rows) == sync domain
  const int bu = lid >> 2;    // unit strip (16 cols), 0..31
  const int m0 = bb * 32;
  const int u0 = bu * 16;
  const int gcol = wave * H_ + u0 + lr;  // this lane's gate-column in [0,2048)

  const __hip_bfloat16* Wht = grp ? wh2 : wh1;
  const __hip_bfloat16* Wxt = grp ? wx2 : wx1;
  const __hip_bfloat16* xsrc = grp ? (const __hip_bfloat16*)seq : h0;
  const float* bias = grp ? bl2 : bl1;
  __hip_bfloat16* hb0 = grp ? h2A : h1A;
  __hip_bfloat16* hb1 = grp ? h2B : h1B;
  unsigned* dflags = flags + bb * 64;
  const int didx = (grp << 5) | bu;      // index within domain, 0..63

  char* whs = smem + WH_OFF + wave * 16384;
  char* wxs = smem + WX_OFF + wave * 16384;
  float* gld = (float*)(smem + G_OFF);   // g[gate][m][u] as [4][32][17]

  const float bias0 = bias[gcol];

  // epilogue mapping (static per thread): row m_e, unit pair 2*up_e, 2*up_e+1
  const int m_e = tid >> 3;
  const int up_e = tid & 7;
  float2 creg = {0.f, 0.f};

  // ---- stage this wave's weight slices into LDS, fragment order (once) ----
  {
    const __hip_bfloat16* hsrcw = Wht + (size_t)gcol * H_ + lk * 8;
    const __hip_bfloat16* xsrcw = Wxt + (size_t)gcol * H_ + lk * 8;
#pragma unroll
    for (int i = 0; i < 16; i++) {
      *(bf16x8*)(whs + i * 1024 + lane * 16) = *(const bf16x8*)(hsrcw + i * 32);
      *(bf16x8*)(wxs + i * 1024 + lane * 16) = *(const bf16x8*)(xsrcw + i * 32);
    }
  }
  __syncthreads();

  for (int s = 0; s <= T_; s++) {
    const int t = grp ? (s - 1) : s;
    const bool active = grp ? (s >= 1) : (s < T_);
    if (active) {
      const __hip_bfloat16* hin = (t & 1) ? hb1 : hb0;
      __hip_bfloat16* hout = (t & 1) ? hb0 : hb1;

      // ---- burst-load ALL A-fragments for this step into registers ----
      bf16x8 ah0[16], ah1[16], ax0[16], ax1[16];
      {
        const __hip_bfloat16* a0p = hin + (size_t)(m0 + lr) * H_ + lk * 8;
        const __hip_bfloat16* a1p = a0p + 16 * H_;
#pragma unroll
        for (int i = 0; i < 16; i++) {
          ah0[i] = *(const bf16x8*)(a0p + i * 32);
          ah1[i] = *(const bf16x8*)(a1p + i * 32);
        }
      }
      {
        const __hip_bfloat16* b0p = xsrc + ((size_t)(m0 + lr) * T_ + t) * H_ + lk * 8;
        const __hip_bfloat16* b1p = xsrc + ((size_t)(m0 + 16 + lr) * T_ + t) * H_ + lk * 8;
#pragma unroll
        for (int i = 0; i < 16; i++) {
          ax0[i] = *(const bf16x8*)(b0p + i * 32);
          ax1[i] = *(const bf16x8*)(b1p + i * 32);
        }
      }

      f32x4 acc0 = {0.f, 0.f, 0.f, 0.f};   // batch rows m0..m0+15
      f32x4 acc1 = {0.f, 0.f, 0.f, 0.f};   // batch rows m0+16..m0+31

      // K-loop 1: h_prev @ Wh (A regs, B from LDS)
#pragma unroll
      for (int i = 0; i < 16; i++) {
        bf16x8 bw = *(bf16x8*)(whs + i * 1024 + lane * 16);
        acc0 = __builtin_amdgcn_mfma_f32_16x16x32_bf16(ah0[i], bw, acc0, 0, 0, 0);
        acc1 = __builtin_amdgcn_mfma_f32_16x16x32_bf16(ah1[i], bw, acc1, 0, 0, 0);
      }
      // K-loop 2: x_t @ Wx (A regs, B from LDS)
#pragma unroll
      for (int i = 0; i < 16; i++) {
        bf16x8 bw = *(bf16x8*)(wxs + i * 1024 + lane * 16);
        acc0 = __builtin_amdgcn_mfma_f32_16x16x32_bf16(ax0[i], bw, acc0, 0, 0, 0);
        acc1 = __builtin_amdgcn_mfma_f32_16x16x32_bf16(ax1[i], bw, acc1, 0, 0, 0);
      }

      // stage pre-activation gates in LDS: g[gate][m][u]
#pragma unroll
      for (int r = 0; r < 4; r++) {
        // C/D layout: col = lane&15, row = (lane>>4)*4 + r
        gld[wave * 544 + (lk * 4 + r) * 17 + lr]      = acc0[r] + bias0;
        gld[wave * 544 + (16 + lk * 4 + r) * 17 + lr] = acc1[r] + bias0;
      }
      __syncthreads();

      // elementwise: thread handles (m_e, units 2*up_e, 2*up_e+1)
      {
        const int gbase0 = m_e * 17 + 2 * up_e;
        float i0 = sigmoidf_(gld[0 * 544 + gbase0]);
        float i1 = sigmoidf_(gld[0 * 544 + gbase0 + 1]);
        float f0 = sigmoidf_(gld[1 * 544 + gbase0]);
        float f1 = sigmoidf_(gld[1 * 544 + gbase0 + 1]);
        float cb0 = tanhf(gld[2 * 544 + gbase0]);
        float cb1 = tanhf(gld[2 * 544 + gbase0 + 1]);
        float o0 = sigmoidf_(gld[3 * 544 + gbase0]);
        float o1 = sigmoidf_(gld[3 * 544 + gbase0 + 1]);
        float cn0 = f0 * creg.x + i0 * cb0;
        float cn1 = f1 * creg.y + i1 * cb1;
        creg.x = cn0; creg.y = cn1;
        float hv0 = o0 * tanhf(cn0);
        float hv1 = o1 * tanhf(cn1);
        union { __hip_bfloat16 h[2]; unsigned u; } pk;
        pk.h[0] = __float2bfloat16(hv0);
        pk.h[1] = __float2bfloat16(hv1);
        const int row = m0 + m_e;
        const int col = u0 + 2 * up_e;
        coh_store_u32((unsigned*)hout + (row * H_ + col) / 2, pk.u);
        if (grp == 0) {
          coh_store_u32((unsigned*)seq + (((size_t)row * T_ + t) * H_ + col) / 2, pk.u);
        } else if (t == T_ - 1) {
          float2* dst = (float2*)(h2f + row * H_ + col);
          float2 hv = {hv0, hv1};
          *dst = hv;   // plain: kernel-end flush covers final_k
        }
      }
    }
    if (s < T_) dom_barrier(dflags, didx, tid, (unsigned)(s + 1));
  }
}

// ---- LayerNorm + dense2(relu) + dense3; one block per batch row ----
__global__ __launch_bounds__(256) void final_k(
    const float* __restrict__ h2, const float* __restrict__ gamma, const float* __restrict__ beta,
    const float* __restrict__ W2, const float* __restrict__ b2,
    const float* __restrict__ W3, const float* __restrict__ b3, float* __restrict__ out)
{
  __shared__ float y[512];
  __shared__ float redS[4], redQ[4], redP[4];
  int b = blockIdx.x, tid = threadIdx.x;
  int wave = tid >> 6, lane = tid & 63;
  float v0 = h2[b * H_ + tid], v1 = h2[b * H_ + 256 + tid];
  float s = v0 + v1, q = v0 * v0 + v1 * v1;
#pragma unroll
  for (int o = 32; o; o >>= 1) { s += __shfl_down(s, o); q += __shfl_down(q, o); }
  if (lane == 0) { redS[wave] = s; redQ[wave] = q; }
  __syncthreads();
  float tot = redS[0] + redS[1] + redS[2] + redS[3];
  float totq = redQ[0] + redQ[1] + redQ[2] + redQ[3];
  float mu = tot * (1.f / 512.f);
  float var = totq * (1.f / 512.f) - mu * mu;
  float rs = rsqrtf(var + 1e-3f);
  y[tid]       = (v0 - mu) * rs * gamma[tid] + beta[tid];
  y[tid + 256] = (v1 - mu) * rs * gamma[tid + 256] + beta[tid + 256];
  __syncthreads();
  float acc = b2[tid];
  for (int k = 0; k < 512; k++) acc += y[k] * W2[k * 256 + tid];
  float pv = fmaxf(acc, 0.f) * W3[tid];
#pragma unroll
  for (int o = 32; o; o >>= 1) pv += __shfl_down(pv, o);
  if (lane == 0) redP[wave] = pv;
  __syncthreads();
  if (tid == 0) out[b] = redP[0] + redP[1] + redP[2] + redP[3] + b3[0];
}

extern "C" void kernel_launch(void* const* d_in, const int* in_sizes, int n_in,
                              void* d_out, int out_size, void* d_ws, size_t ws_size,
                              hipStream_t stream)
{
  (void)in_sizes; (void)n_in; (void)out_size; (void)ws_size;
  const float* x    = (const float*)d_in[0];
  const float* W1   = (const float*)d_in[1];
  const float* b1   = (const float*)d_in[2];
  const float* Wx1  = (const float*)d_in[3];
  const float* Wh1  = (const float*)d_in[4];
  const float* bl1  = (const float*)d_in[5];
  const float* Wx2  = (const float*)d_in[6];
  const float* Wh2  = (const float*)d_in[7];
  const float* bl2  = (const float*)d_in[8];
  const float* gam  = (const float*)d_in[9];
  const float* bet  = (const float*)d_in[10];
  const float* W2   = (const float*)d_in[11];
  const float* b2   = (const float*)d_in[12];
  const float* W3   = (const float*)d_in[13];
  const float* b3   = (const float*)d_in[14];

  char* p = (char*)d_ws;
  const size_t MB = 1024 * 1024;
  __hip_bfloat16* wx1t = (__hip_bfloat16*)(p + 0 * MB);
  __hip_bfloat16* wh1t = (__hip_bfloat16*)(p + 2 * MB);
  __hip_bfloat16* wx2t = (__hip_bfloat16*)(p + 4 * MB);
  __hip_bfloat16* wh2t = (__hip_bfloat16*)(p + 6 * MB);
  __hip_bfloat16* w1b  = (__hip_bfloat16*)(p + 8 * MB);
  __hip_bfloat16* h0   = (__hip_bfloat16*)(p + 9 * MB);   // 32 MB
  __hip_bfloat16* seq  = (__hip_bfloat16*)(p + 41 * MB);  // 32 MB
  char* st = p + 73 * MB;
  __hip_bfloat16* h1A = (__hip_bfloat16*)st;                       // 4x128KB
  __hip_bfloat16* h1B = h1A + B_ * H_;
  __hip_bfloat16* h2A = h1B + B_ * H_;
  __hip_bfloat16* h2B = h2A + B_ * H_;
  float* h2f = (float*)(st + 512 * 1024);                          // 256KB
  unsigned* flags = (unsigned*)(st + 512 * 1024 + 256 * 1024);     // 1KB used
  int nzero = (int)((512 * 1024 + 256 * 1024 + 4096) / 4);

  transpose_cast_k<<<dim3(32, 8, 4), 256, 0, stream>>>(Wx1, Wh1, Wx2, Wh2, wx1t);
  prep_misc_k<<<256, 256, 0, stream>>>(W1, w1b, (float*)st, nzero);
  dense1_k<<<1024, 512, 0, stream>>>(x, w1b, b1, h0);

  void* args[] = { (void*)&h0, (void*)&seq,
                   (void*)&wh1t, (void*)&wx1t, (void*)&bl1,
                   (void*)&wh2t, (void*)&wx2t, (void*)&bl2,
                   (void*)&h1A, (void*)&h1B, (void*)&h2A, (void*)&h2B,
                   (void*)&h2f, (void*)&flags };
  hipLaunchCooperativeKernel((void*)lstm_fused_k, dim3(256), dim3(256), args,
                             SMEM_TOTAL, stream);

  final_k<<<128, 256, 0, stream>>>(h2f, gam, bet, W2, b2, W3, b3, (float*)d_out);
}

// Round 9
// 3826.425 us; speedup vs baseline: 1.2217x; 1.2217x over previous
//
#include <hip/hip_runtime.h>
#include <hip/hip_bf16.h>
#include <math.h>

#define B_ 128
#define T_ 256
#define F_ 64
#define H_ 512
#define G4_ 2048

// dynamic LDS layout (bytes)
#define WH_OFF 0        // 4 waves x 16KB Wh fragments
#define WX_OFF 65536    // 4 waves x 16KB Wx fragments
#define ST_OFF 131072   // 16KB staging for A-tiles (reused for g[4][32][17] f32)
#define SMEM_TOTAL 147456

typedef __attribute__((ext_vector_type(8))) short bf16x8;
typedef __attribute__((ext_vector_type(4))) float f32x4;

__device__ __forceinline__ float sigmoidf_(float x) { return 1.f / (1.f + expf(-x)); }

__device__ __forceinline__ void coh_store_u32(unsigned* p, unsigned v) {
  __hip_atomic_store(p, v, __ATOMIC_RELAXED, __HIP_MEMORY_SCOPE_AGENT);
}
__device__ __forceinline__ unsigned coh_load_u32(const unsigned* p) {
  return __hip_atomic_load(p, __ATOMIC_RELAXED, __HIP_MEMORY_SCOPE_AGENT);
}

// async 16B/lane global->LDS copy; LDS dest = uniform base + lane*16 (HW rule)
__device__ __forceinline__ void async_ld16(const void* g, void* l) {
  __builtin_amdgcn_global_load_lds(
      (const __attribute__((address_space(1))) void*)g,
      (__attribute__((address_space(3))) void*)l, 16, 0, 0);
}

// Domain barrier over 64 blocks (one batch-strip's grp0+grp1 blocks).
// All-poll-all flags + agent acquire-fence (L1/L2 invalidate) so subsequent
// loads refetch fresh data. Weights are LDS-resident (fence-immune).
__device__ __forceinline__ void dom_barrier(unsigned* dflags, int idx, int tid,
                                            unsigned s1) {
  asm volatile("s_waitcnt vmcnt(0)" ::: "memory");  // data stores at IF
  __syncthreads();                                  // whole block drained
  if (tid == 0) coh_store_u32(&dflags[idx], s1);
  if (tid < 64) {
    while (coh_load_u32(&dflags[tid]) < s1) __builtin_amdgcn_s_sleep(8);
  }
  __syncthreads();
  __builtin_amdgcn_fence(__ATOMIC_ACQUIRE, "agent");  // invalidate L1/L2
}

// ---- transpose+cast four [512,2048] fp32 weight mats -> [2048,512] bf16 ----
__global__ __launch_bounds__(256) void transpose_cast_k(
    const float* __restrict__ s0, const float* __restrict__ s1,
    const float* __restrict__ s2, const float* __restrict__ s3,
    __hip_bfloat16* __restrict__ dst)
{
  __shared__ float lds[64][65];
  const float* src = (blockIdx.z == 0) ? s0 : (blockIdx.z == 1) ? s1 : (blockIdx.z == 2) ? s2 : s3;
  __hip_bfloat16* d = dst + (size_t)blockIdx.z * (G4_ * H_);
  int n0 = blockIdx.x * 64, k0 = blockIdx.y * 64;
  int tx = threadIdx.x & 63, ty = threadIdx.x >> 6;
#pragma unroll
  for (int r = 0; r < 16; r++) { int k = r * 4 + ty; lds[k][tx] = src[(size_t)(k0 + k) * G4_ + n0 + tx]; }
  __syncthreads();
#pragma unroll
  for (int r = 0; r < 16; r++) { int n = r * 4 + ty; d[(size_t)(n0 + n) * H_ + k0 + tx] = __float2bfloat16(lds[tx][n]); }
}

// ---- cast W1 to bf16 + zero state buffers & barrier flags ----
__global__ void prep_misc_k(const float* __restrict__ w1, __hip_bfloat16* __restrict__ w1b,
                            float* __restrict__ zbase, int nzero)
{
  int i = blockIdx.x * blockDim.x + threadIdx.x;
  int stride = gridDim.x * blockDim.x;
  for (int k = i; k < F_ * H_; k += stride) w1b[k] = __float2bfloat16(w1[k]);
  for (int k = i; k < nzero; k += stride) zbase[k] = 0.f;
}

// ---- dense1 + spectral-norm row normalization; h0 out as bf16 [B*T, H] ----
__global__ __launch_bounds__(512) void dense1_k(
    const float* __restrict__ x, const __hip_bfloat16* __restrict__ w1b,
    const float* __restrict__ b1, __hip_bfloat16* __restrict__ h0)
{
  __shared__ float red[8];
  int j = threadIdx.x;
  int wave = j >> 6, lane = j & 63;
  float wcol[64];
#pragma unroll
  for (int k = 0; k < 64; k++) wcol[k] = __bfloat162float(w1b[k * H_ + j]);
  float bj = b1[j];
  for (int r = 0; r < 32; r++) {
    int row = blockIdx.x * 32 + r;
    const float* xr = x + (size_t)row * F_;
    float acc = bj;
#pragma unroll
    for (int k = 0; k < 64; k++) acc += xr[k] * wcol[k];
    float ss = acc * acc;
#pragma unroll
    for (int o = 32; o; o >>= 1) ss += __shfl_down(ss, o);
    if (lane == 0) red[wave] = ss;
    __syncthreads();
    float tot = red[0] + red[1] + red[2] + red[3] + red[4] + red[5] + red[6] + red[7];
    float sc = sqrtf(512.f) / fmaxf(sqrtf(tot), 1e-12f);
    h0[(size_t)row * H_ + j] = __float2bfloat16(acc * sc);
    __syncthreads();
  }
}

// ---- fused persistent LSTM1+LSTM2, diagonally pipelined, weights in LDS ----
// 256 blocks (1/CU): grp0 = blocks 0..127 run LSTM1 step s; grp1 = 128..255
// run LSTM2 step s-1. Per grp: 4 batch-strips(32) x 32 unit-strips(16).
// Wave w = gate w over a 32(batch)x16(unit) tile, K=1024 (h@Wh + x@Wx).
// Round 9: A-fragments staged via global_load_lds (async direct-to-LDS, no
// data VGPRs). r5-r8 showed the K-loop is issue-window-bound: at VGPR=40 only
// ~5 plain loads fit in flight -> ~10 serialized ~900cy IF misses = 17us/step;
// forcing a VGPR burst (r3/r8, ~300 VGPRs) makes the cooperative launch get
// REJECTED (zero-output signature). global_load_lds has no register
// dependency: 16 x 1KB loads per round issue back-to-back (one latency
// round), VGPR count stays in the proven-launchable regime. Also cuts global
// A-traffic 4x (waves share the staged tile).
__global__ __launch_bounds__(256) void lstm_fused_k(
    const __hip_bfloat16* __restrict__ h0,     // [B*T, H] dense1 output (LSTM1 x)
    __hip_bfloat16* __restrict__ seq,          // [B*T, H] LSTM1 out / LSTM2 x
    const __hip_bfloat16* __restrict__ wh1, const __hip_bfloat16* __restrict__ wx1,
    const float* __restrict__ bl1,
    const __hip_bfloat16* __restrict__ wh2, const __hip_bfloat16* __restrict__ wx2,
    const float* __restrict__ bl2,
    __hip_bfloat16* __restrict__ h1A, __hip_bfloat16* __restrict__ h1B,
    __hip_bfloat16* __restrict__ h2A, __hip_bfloat16* __restrict__ h2B,
    float* __restrict__ h2f,                   // [B, H] fp32 final h of LSTM2
    unsigned* flags)                           // 4 domains x 64 flags
{
  extern __shared__ char smem[];
  const int tid = threadIdx.x;
  const int wave = tid >> 6;
  const int lane = tid & 63;
  const int lr = lane & 15;   // m (A-rows) / n (B-cols) within 16-tile
  const int lk = lane >> 4;   // k-octet quad
  const int bid = blockIdx.x;
  const int grp = bid >> 7;
  const int lid = bid & 127;
  const int bb = lid & 3;     // batch strip (32 rows) == sync domain
  const int bu = lid >> 2;    // unit strip (16 cols), 0..31
  const int m0 = bb * 32;
  const int u0 = bu * 16;
  const int gcol = wave * H_ + u0 + lr;  // this lane's gate-column in [0,2048)

  const __hip_bfloat16* Wht = grp ? wh2 : wh1;
  const __hip_bfloat16* Wxt = grp ? wx2 : wx1;
  const __hip_bfloat16* xsrc = grp ? (const __hip_bfloat16*)seq : h0;
  const float* bias = grp ? bl2 : bl1;
  __hip_bfloat16* hb0 = grp ? h2A : h1A;
  __hip_bfloat16* hb1 = grp ? h2B : h1B;
  unsigned* dflags = flags + bb * 64;
  const int didx = (grp << 5) | bu;      // index within domain, 0..63

  char* whs = smem + WH_OFF + wave * 16384;
  char* wxs = smem + WX_OFF + wave * 16384;
  char* stg = smem + ST_OFF;             // 16KB A-staging (g[] reuses it)
  float* gld = (float*)(smem + ST_OFF);  // g[gate][m][u] as [4][32][17]

  const float bias0 = bias[gcol];

  // epilogue mapping (static per thread): row m_e, unit pair 2*up_e, 2*up_e+1
  const int m_e = tid >> 3;
  const int up_e = tid & 7;
  float2 creg = {0.f, 0.f};

  // ---- stage this wave's weight slices into LDS, fragment order (once) ----
  {
    const __hip_bfloat16* hsrcw = Wht + (size_t)gcol * H_ + lk * 8;
    const __hip_bfloat16* xsrcw = Wxt + (size_t)gcol * H_ + lk * 8;
#pragma unroll
    for (int i = 0; i < 16; i++) {
      *(bf16x8*)(whs + i * 1024 + lane * 16) = *(const bf16x8*)(hsrcw + i * 32);
      *(bf16x8*)(wxs + i * 1024 + lane * 16) = *(const bf16x8*)(xsrcw + i * 32);
    }
  }
  __syncthreads();

  for (int s = 0; s <= T_; s++) {
    const int t = grp ? (s - 1) : s;
    const bool active = grp ? (s >= 1) : (s < T_);
    if (active) {
      const __hip_bfloat16* hin = (t & 1) ? hb1 : hb0;
      __hip_bfloat16* hout = (t & 1) ? hb0 : hb1;

      f32x4 acc0 = {0.f, 0.f, 0.f, 0.f};   // batch rows m0..m0+15
      f32x4 acc1 = {0.f, 0.f, 0.f, 0.f};   // batch rows m0+16..m0+31

      // round sources: R0/R1 = h rows lo/hi (weights whs -> acc0/acc1),
      //                R2/R3 = x rows lo/hi (weights wxs -> acc0/acc1)
#pragma unroll
      for (int rnd = 0; rnd < 4; rnd++) {
        const __hip_bfloat16* gbase;
        if (rnd == 0)      gbase = hin  + (size_t)(m0 + lr) * H_ + lk * 8;
        else if (rnd == 1) gbase = hin  + (size_t)(m0 + 16 + lr) * H_ + lk * 8;
        else if (rnd == 2) gbase = xsrc + ((size_t)(m0 + lr) * T_ + t) * H_ + lk * 8;
        else               gbase = xsrc + ((size_t)(m0 + 16 + lr) * T_ + t) * H_ + lk * 8;
        // each wave issues 4 of the 16 chunks, all in flight together
#pragma unroll
        for (int j = 0; j < 4; j++) {
          const int c = wave * 4 + j;
          async_ld16(gbase + c * 32, stg + c * 1024);
        }
        asm volatile("s_waitcnt vmcnt(0)" ::: "memory");
        __syncthreads();
        const char* wsl = (rnd < 2) ? whs : wxs;
        f32x4* acc = (rnd & 1) ? &acc1 : &acc0;
        f32x4 a = *acc;
#pragma unroll
        for (int i = 0; i < 16; i++) {
          bf16x8 av = *(const bf16x8*)(stg + i * 1024 + lane * 16);
          bf16x8 bw = *(const bf16x8*)(wsl + i * 1024 + lane * 16);
          a = __builtin_amdgcn_mfma_f32_16x16x32_bf16(av, bw, a, 0, 0, 0);
        }
        *acc = a;
        __syncthreads();   // staging buffer free for next round
      }

      // stage pre-activation gates in LDS (reuse staging region)
#pragma unroll
      for (int r = 0; r < 4; r++) {
        // C/D layout: col = lane&15, row = (lane>>4)*4 + r
        gld[wave * 544 + (lk * 4 + r) * 17 + lr]      = acc0[r] + bias0;
        gld[wave * 544 + (16 + lk * 4 + r) * 17 + lr] = acc1[r] + bias0;
      }
      __syncthreads();

      // elementwise: thread handles (m_e, units 2*up_e, 2*up_e+1)
      {
        const int gbase0 = m_e * 17 + 2 * up_e;
        float i0 = sigmoidf_(gld[0 * 544 + gbase0]);
        float i1 = sigmoidf_(gld[0 * 544 + gbase0 + 1]);
        float f0 = sigmoidf_(gld[1 * 544 + gbase0]);
        float f1 = sigmoidf_(gld[1 * 544 + gbase0 + 1]);
        float cb0 = tanhf(gld[2 * 544 + gbase0]);
        float cb1 = tanhf(gld[2 * 544 + gbase0 + 1]);
        float o0 = sigmoidf_(gld[3 * 544 + gbase0]);
        float o1 = sigmoidf_(gld[3 * 544 + gbase0 + 1]);
        float cn0 = f0 * creg.x + i0 * cb0;
        float cn1 = f1 * creg.y + i1 * cb1;
        creg.x = cn0; creg.y = cn1;
        float hv0 = o0 * tanhf(cn0);
        float hv1 = o1 * tanhf(cn1);
        union { __hip_bfloat16 h[2]; unsigned u; } pk;
        pk.h[0] = __float2bfloat16(hv0);
        pk.h[1] = __float2bfloat16(hv1);
        const int row = m0 + m_e;
        const int col = u0 + 2 * up_e;
        coh_store_u32((unsigned*)hout + (row * H_ + col) / 2, pk.u);
        if (grp == 0) {
          coh_store_u32((unsigned*)seq + (((size_t)row * T_ + t) * H_ + col) / 2, pk.u);
        } else if (t == T_ - 1) {
          float2* dst = (float2*)(h2f + row * H_ + col);
          float2 hv = {hv0, hv1};
          *dst = hv;   // plain: kernel-end flush covers final_k
        }
      }
    }
    if (s < T_) dom_barrier(dflags, didx, tid, (unsigned)(s + 1));
  }
}

// ---- LayerNorm + dense2(relu) + dense3; one block per batch row ----
__global__ __launch_bounds__(256) void final_k(
    const float* __restrict__ h2, const float* __restrict__ gamma, const float* __restrict__ beta,
    const float* __restrict__ W2, const float* __restrict__ b2,
    const float* __restrict__ W3, const float* __restrict__ b3, float* __restrict__ out)
{
  __shared__ float y[512];
  __shared__ float redS[4], redQ[4], redP[4];
  int b = blockIdx.x, tid = threadIdx.x;
  int wave = tid >> 6, lane = tid & 63;
  float v0 = h2[b * H_ + tid], v1 = h2[b * H_ + 256 + tid];
  float s = v0 + v1, q = v0 * v0 + v1 * v1;
#pragma unroll
  for (int o = 32; o; o >>= 1) { s += __shfl_down(s, o); q += __shfl_down(q, o); }
  if (lane == 0) { redS[wave] = s; redQ[wave] = q; }
  __syncthreads();
  float tot = redS[0] + redS[1] + redS[2] + redS[3];
  float totq = redQ[0] + redQ[1] + redQ[2] + redQ[3];
  float mu = tot * (1.f / 512.f);
  float var = totq * (1.f / 512.f) - mu * mu;
  float rs = rsqrtf(var + 1e-3f);
  y[tid]       = (v0 - mu) * rs * gamma[tid] + beta[tid];
  y[tid + 256] = (v1 - mu) * rs * gamma[tid + 256] + beta[tid + 256];
  __syncthreads();
  float acc = b2[tid];
  for (int k = 0; k < 512; k++) acc += y[k] * W2[k * 256 + tid];
  float pv = fmaxf(acc, 0.f) * W3[tid];
#pragma unroll
  for (int o = 32; o; o >>= 1) pv += __shfl_down(pv, o);
  if (lane == 0) redP[wave] = pv;
  __syncthreads();
  if (tid == 0) out[b] = redP[0] + redP[1] + redP[2] + redP[3] + b3[0];
}

extern "C" void kernel_launch(void* const* d_in, const int* in_sizes, int n_in,
                              void* d_out, int out_size, void* d_ws, size_t ws_size,
                              hipStream_t stream)
{
  (void)in_sizes; (void)n_in; (void)out_size; (void)ws_size;
  const float* x    = (const float*)d_in[0];
  const float* W1   = (const float*)d_in[1];
  const float* b1   = (const float*)d_in[2];
  const float* Wx1  = (const float*)d_in[3];
  const float* Wh1  = (const float*)d_in[4];
  const float* bl1  = (const float*)d_in[5];
  const float* Wx2  = (const float*)d_in[6];
  const float* Wh2  = (const float*)d_in[7];
  const float* bl2  = (const float*)d_in[8];
  const float* gam  = (const float*)d_in[9];
  const float* bet  = (const float*)d_in[10];
  const float* W2   = (const float*)d_in[11];
  const float* b2   = (const float*)d_in[12];
  const float* W3   = (const float*)d_in[13];
  const float* b3   = (const float*)d_in[14];

  char* p = (char*)d_ws;
  const size_t MB = 1024 * 1024;
  __hip_bfloat16* wx1t = (__hip_bfloat16*)(p + 0 * MB);
  __hip_bfloat16* wh1t = (__hip_bfloat16*)(p + 2 * MB);
  __hip_bfloat16* wx2t = (__hip_bfloat16*)(p + 4 * MB);
  __hip_bfloat16* wh2t = (__hip_bfloat16*)(p + 6 * MB);
  __hip_bfloat16* w1b  = (__hip_bfloat16*)(p + 8 * MB);
  __hip_bfloat16* h0   = (__hip_bfloat16*)(p + 9 * MB);   // 32 MB
  __hip_bfloat16* seq  = (__hip_bfloat16*)(p + 41 * MB);  // 32 MB
  char* st = p + 73 * MB;
  __hip_bfloat16* h1A = (__hip_bfloat16*)st;                       // 4x128KB
  __hip_bfloat16* h1B = h1A + B_ * H_;
  __hip_bfloat16* h2A = h1B + B_ * H_;
  __hip_bfloat16* h2B = h2A + B_ * H_;
  float* h2f = (float*)(st + 512 * 1024);                          // 256KB
  unsigned* flags = (unsigned*)(st + 512 * 1024 + 256 * 1024);     // 1KB used
  int nzero = (int)((512 * 1024 + 256 * 1024 + 4096) / 4);

  transpose_cast_k<<<dim3(32, 8, 4), 256, 0, stream>>>(Wx1, Wh1, Wx2, Wh2, wx1t);
  prep_misc_k<<<256, 256, 0, stream>>>(W1, w1b, (float*)st, nzero);
  dense1_k<<<1024, 512, 0, stream>>>(x, w1b, b1, h0);

  void* args[] = { (void*)&h0, (void*)&seq,
                   (void*)&wh1t, (void*)&wx1t, (void*)&bl1,
                   (void*)&wh2t, (void*)&wx2t, (void*)&bl2,
                   (void*)&h1A, (void*)&h1B, (void*)&h2A, (void*)&h2B,
                   (void*)&h2f, (void*)&flags };
  hipLaunchCooperativeKernel((void*)lstm_fused_k, dim3(256), dim3(256), args,
                             SMEM_TOTAL, stream);

  final_k<<<128, 256, 0, stream>>>(h2f, gam, bet, W2, b2, W3, b3, (float*)d_out);
}

// Round 10
// 3096.615 us; speedup vs baseline: 1.5097x; 1.2357x over previous
//
#include <hip/hip_runtime.h>
#include <hip/hip_bf16.h>
#include <math.h>

#define B_ 128
#define T_ 256
#define F_ 64
#define H_ 512
#define G4_ 2048

// dynamic LDS layout (bytes)
#define WH_OFF 0        // 4 waves x 16KB Wh fragments
#define WX_OFF 65536    // 4 waves x 16KB Wx fragments
#define ST_OFF 131072   // 16KB staging: 2 x 8KB ping-pong (g[4][32][17] overlays)
#define SMEM_TOTAL 147456

typedef __attribute__((ext_vector_type(8))) short bf16x8;
typedef __attribute__((ext_vector_type(4))) float f32x4;

__device__ __forceinline__ float sigmoidf_(float x) { return 1.f / (1.f + expf(-x)); }

__device__ __forceinline__ void coh_store_u32(unsigned* p, unsigned v) {
  __hip_atomic_store(p, v, __ATOMIC_RELAXED, __HIP_MEMORY_SCOPE_AGENT);
}
__device__ __forceinline__ unsigned coh_load_u32(const unsigned* p) {
  return __hip_atomic_load(p, __ATOMIC_RELAXED, __HIP_MEMORY_SCOPE_AGENT);
}
__device__ __forceinline__ void rawbar() { __builtin_amdgcn_s_barrier(); }

// async 16B/lane global->LDS copy; LDS dest = uniform base + lane*16 (HW rule)
__device__ __forceinline__ void async_ld16(const void* g, void* l) {
  __builtin_amdgcn_global_load_lds(
      (const __attribute__((address_space(1))) void*)g,
      (__attribute__((address_space(3))) void*)l, 16, 0, 0);
}

// ---- transpose+cast four [512,2048] fp32 weight mats -> [2048,512] bf16 ----
__global__ __launch_bounds__(256) void transpose_cast_k(
    const float* __restrict__ s0, const float* __restrict__ s1,
    const float* __restrict__ s2, const float* __restrict__ s3,
    __hip_bfloat16* __restrict__ dst)
{
  __shared__ float lds[64][65];
  const float* src = (blockIdx.z == 0) ? s0 : (blockIdx.z == 1) ? s1 : (blockIdx.z == 2) ? s2 : s3;
  __hip_bfloat16* d = dst + (size_t)blockIdx.z * (G4_ * H_);
  int n0 = blockIdx.x * 64, k0 = blockIdx.y * 64;
  int tx = threadIdx.x & 63, ty = threadIdx.x >> 6;
#pragma unroll
  for (int r = 0; r < 16; r++) { int k = r * 4 + ty; lds[k][tx] = src[(size_t)(k0 + k) * G4_ + n0 + tx]; }
  __syncthreads();
#pragma unroll
  for (int r = 0; r < 16; r++) { int n = r * 4 + ty; d[(size_t)(n0 + n) * H_ + k0 + tx] = __float2bfloat16(lds[tx][n]); }
}

// ---- cast W1 to bf16 + zero state buffers & barrier flags ----
__global__ void prep_misc_k(const float* __restrict__ w1, __hip_bfloat16* __restrict__ w1b,
                            float* __restrict__ zbase, int nzero)
{
  int i = blockIdx.x * blockDim.x + threadIdx.x;
  int stride = gridDim.x * blockDim.x;
  for (int k = i; k < F_ * H_; k += stride) w1b[k] = __float2bfloat16(w1[k]);
  for (int k = i; k < nzero; k += stride) zbase[k] = 0.f;
}

// ---- dense1 + spectral-norm row normalization; h0 out as bf16 [B*T, H] ----
__global__ __launch_bounds__(512) void dense1_k(
    const float* __restrict__ x, const __hip_bfloat16* __restrict__ w1b,
    const float* __restrict__ b1, __hip_bfloat16* __restrict__ h0)
{
  __shared__ float red[8];
  int j = threadIdx.x;
  int wave = j >> 6, lane = j & 63;
  float wcol[64];
#pragma unroll
  for (int k = 0; k < 64; k++) wcol[k] = __bfloat162float(w1b[k * H_ + j]);
  float bj = b1[j];
  for (int r = 0; r < 32; r++) {
    int row = blockIdx.x * 32 + r;
    const float* xr = x + (size_t)row * F_;
    float acc = bj;
#pragma unroll
    for (int k = 0; k < 64; k++) acc += xr[k] * wcol[k];
    float ss = acc * acc;
#pragma unroll
    for (int o = 32; o; o >>= 1) ss += __shfl_down(ss, o);
    if (lane == 0) red[wave] = ss;
    __syncthreads();
    float tot = red[0] + red[1] + red[2] + red[3] + red[4] + red[5] + red[6] + red[7];
    float sc = sqrtf(512.f) / fmaxf(sqrtf(tot), 1e-12f);
    h0[(size_t)row * H_ + j] = __float2bfloat16(acc * sc);
    __syncthreads();
  }
}

// ---- fused persistent LSTM1+LSTM2, decoupled producer/consumer ----
// 256 blocks (1/CU): grp0 = LSTM1 (free-running producer), grp1 = LSTM2
// (consumer, lag>=2). Per grp per batch-strip: 32 unit-blocks exchange h each
// step via flags + agent stores; weights LDS-resident (fence-immune).
// Round 10: (a) split barriers — grp0 polls only its own 32 flags (it reads
// nothing grp1 writes; seq slots are write-once), grp1 polls its own 32 +
// requires grp0 >= u+2 (enables legal x-prefetch); (b) x-tile prefetched
// PRE-barrier (latency overlaps barrier wait); (c) h/x loads pipelined as
// 8 x 8KB sub-rounds ping-ponged through 16KB staging with raw s_barrier +
// per-wave s_waitcnt vmcnt(2) — exposed latency ~1 RT instead of 4 serial.
__global__ __launch_bounds__(256) void lstm_fused_k(
    const __hip_bfloat16* __restrict__ h0,     // [B*T, H] dense1 output (LSTM1 x)
    __hip_bfloat16* __restrict__ seq,          // [B*T, H] LSTM1 out / LSTM2 x
    const __hip_bfloat16* __restrict__ wh1, const __hip_bfloat16* __restrict__ wx1,
    const float* __restrict__ bl1,
    const __hip_bfloat16* __restrict__ wh2, const __hip_bfloat16* __restrict__ wx2,
    const float* __restrict__ bl2,
    __hip_bfloat16* __restrict__ h1A, __hip_bfloat16* __restrict__ h1B,
    __hip_bfloat16* __restrict__ h2A, __hip_bfloat16* __restrict__ h2B,
    float* __restrict__ h2f,                   // [B, H] fp32 final h of LSTM2
    unsigned* flags)                           // 4 domains x 64 flags
{
  extern __shared__ char smem[];
  const int tid = threadIdx.x;
  const int wave = tid >> 6;
  const int lane = tid & 63;
  const int lr = lane & 15;   // m (A-rows) / n (B-cols) within 16-tile
  const int lk = lane >> 4;   // k-octet quad
  const int bid = blockIdx.x;
  const int grp = bid >> 7;
  const int lid = bid & 127;
  const int bb = lid & 3;     // batch strip (32 rows) == sync domain
  const int bu = lid >> 2;    // unit strip (16 cols), 0..31
  const int m0 = bb * 32;
  const int u0 = bu * 16;
  const int gcol = wave * H_ + u0 + lr;  // this lane's gate-column in [0,2048)

  const __hip_bfloat16* Wht = grp ? wh2 : wh1;
  const __hip_bfloat16* Wxt = grp ? wx2 : wx1;
  const __hip_bfloat16* xsrc = grp ? (const __hip_bfloat16*)seq : h0;
  const float* bias = grp ? bl2 : bl1;
  __hip_bfloat16* hb0 = grp ? h2A : h1A;
  __hip_bfloat16* hb1 = grp ? h2B : h1B;
  unsigned* dflags = flags + bb * 64;
  const int myidx = (grp << 5) | bu;

  char* whs = smem + WH_OFF + wave * 16384;
  char* wxs = smem + WX_OFF + wave * 16384;
  char* stg = smem + ST_OFF;             // 2 x 8KB ping-pong (g overlays)
  float* gld = (float*)(smem + ST_OFF);  // g[gate][m][u] as [4][32][17]

  const float bias0 = bias[gcol];
  const int m_e = tid >> 3;
  const int up_e = tid & 7;
  float2 creg = {0.f, 0.f};

  const __hip_bfloat16* hin = hb0;       // updated per step

  // issue one 8KB sub-round (this wave's 2 chunks) into buf
  auto sub_issue = [&](int type, int half, char* buf, int tx) {
    const __hip_bfloat16* base;
    if (type == 0)      base = hin  + (size_t)(m0 + lr) * H_ + lk * 8;
    else if (type == 1) base = hin  + (size_t)(m0 + 16 + lr) * H_ + lk * 8;
    else if (type == 2) base = xsrc + ((size_t)(m0 + lr) * T_ + tx) * H_ + lk * 8;
    else                base = xsrc + ((size_t)(m0 + 16 + lr) * T_ + tx) * H_ + lk * 8;
#pragma unroll
    for (int j = 0; j < 2; j++) {
      const int kc = half * 8 + wave * 2 + j;
      async_ld16(base + kc * 32, buf + (wave * 2 + j) * 1024);
    }
  };

  f32x4 acc0, acc1;
  // compute one 8KB sub-round: 8 MFMAs from buf + LDS weights
  auto sub_comp = [&](int type, int half, const char* buf) {
    const char* wsl = (type < 2) ? whs : wxs;
    f32x4 a = (type & 1) ? acc1 : acc0;
#pragma unroll
    for (int j = 0; j < 8; j++) {
      const int kc = half * 8 + j;
      bf16x8 av = *(const bf16x8*)(buf + j * 1024 + lane * 16);
      bf16x8 bw = *(const bf16x8*)(wsl + kc * 1024 + lane * 16);
      a = __builtin_amdgcn_mfma_f32_16x16x32_bf16(av, bw, a, 0, 0, 0);
    }
    if (type & 1) acc1 = a; else acc0 = a;
  };

  // ---- stage this wave's weight slices into LDS, fragment order (once) ----
  {
    const __hip_bfloat16* hsrcw = Wht + (size_t)gcol * H_ + lk * 8;
    const __hip_bfloat16* xsrcw = Wxt + (size_t)gcol * H_ + lk * 8;
#pragma unroll
    for (int i = 0; i < 16; i++) {
      *(bf16x8*)(whs + i * 1024 + lane * 16) = *(const bf16x8*)(hsrcw + i * 32);
      *(bf16x8*)(wxs + i * 1024 + lane * 16) = *(const bf16x8*)(xsrcw + i * 32);
    }
  }
  __syncthreads();

  // grp1: wait until grp0 is 2 steps ahead (seq[0], seq[1] published)
  if (grp == 1) {
    if (tid < 32) {
      while (coh_load_u32(&dflags[tid]) < 2u) __builtin_amdgcn_s_sleep(2);
    }
    __syncthreads();
    __builtin_amdgcn_fence(__ATOMIC_ACQUIRE, "agent");
  }

  // initial x prefetch for step 0 (x-lo halves into bufA/bufB)
  sub_issue(2, 0, stg, 0);
  sub_issue(2, 1, stg + 8192, 0);

  // sub-round schedule: Xlo-a, Xlo-b, Hlo-a, Hlo-b, Hhi-a, Hhi-b, Xhi-a, Xhi-b
  const int t_[8]  = {2, 2, 0, 0, 1, 1, 3, 3};
  const int hh_[8] = {0, 1, 0, 1, 0, 1, 0, 1};

  for (int u = 0; u < T_; u++) {
    hin = (u & 1) ? hb1 : hb0;
    __hip_bfloat16* hout = (u & 1) ? hb0 : hb1;

    acc0 = (f32x4){0.f, 0.f, 0.f, 0.f};
    acc1 = (f32x4){0.f, 0.f, 0.f, 0.f};

    // pipelined load+MFMA: ping-pong 8KB sub-rounds
#pragma unroll
    for (int r = 0; r < 8; r++) {
      if (r == 7) asm volatile("s_waitcnt vmcnt(0)" ::: "memory");
      else        asm volatile("s_waitcnt vmcnt(2)" ::: "memory");
      rawbar();
      char* buf = stg + (r & 1) * 8192;
      sub_comp(t_[r], hh_[r], buf);
      rawbar();
      if (r + 2 < 8) sub_issue(t_[r + 2], hh_[r + 2], buf, u);
    }

    // stage pre-activation gates in LDS (overlays staging; safe post-rawbar)
#pragma unroll
    for (int r = 0; r < 4; r++) {
      // C/D layout: col = lane&15, row = (lane>>4)*4 + r
      gld[wave * 544 + (lk * 4 + r) * 17 + lr]      = acc0[r] + bias0;
      gld[wave * 544 + (16 + lk * 4 + r) * 17 + lr] = acc1[r] + bias0;
    }
    __syncthreads();

    // elementwise: thread handles (m_e, units 2*up_e, 2*up_e+1)
    {
      const int gbase0 = m_e * 17 + 2 * up_e;
      float i0 = sigmoidf_(gld[0 * 544 + gbase0]);
      float i1 = sigmoidf_(gld[0 * 544 + gbase0 + 1]);
      float f0 = sigmoidf_(gld[1 * 544 + gbase0]);
      float f1 = sigmoidf_(gld[1 * 544 + gbase0 + 1]);
      float cb0 = tanhf(gld[2 * 544 + gbase0]);
      float cb1 = tanhf(gld[2 * 544 + gbase0 + 1]);
      float o0 = sigmoidf_(gld[3 * 544 + gbase0]);
      float o1 = sigmoidf_(gld[3 * 544 + gbase0 + 1]);
      float cn0 = f0 * creg.x + i0 * cb0;
      float cn1 = f1 * creg.y + i1 * cb1;
      creg.x = cn0; creg.y = cn1;
      float hv0 = o0 * tanhf(cn0);
      float hv1 = o1 * tanhf(cn1);
      union { __hip_bfloat16 h[2]; unsigned u32; } pk;
      pk.h[0] = __float2bfloat16(hv0);
      pk.h[1] = __float2bfloat16(hv1);
      const int row = m0 + m_e;
      const int col = u0 + 2 * up_e;
      coh_store_u32((unsigned*)hout + (row * H_ + col) / 2, pk.u32);
      if (grp == 0) {
        coh_store_u32((unsigned*)seq + (((size_t)row * T_ + u) * H_ + col) / 2, pk.u32);
      } else if (u == T_ - 1) {
        float2* dst = (float2*)(h2f + row * H_ + col);
        float2 hv = {hv0, hv1};
        *dst = hv;   // plain: kernel-end flush covers final_k
      }
    }
    rawbar();   // all g-reads retired (values consumed) before prefetch clobbers

    // prefetch next step's x-lo pre-barrier (grp0: static h0; grp1: seq[u+1],
    // published since grp0 >= u+2 was guaranteed by this step's entry barrier)
    if (u + 1 < T_) {
      sub_issue(2, 0, stg, u + 1);
      sub_issue(2, 1, stg + 8192, u + 1);
      asm volatile("s_waitcnt vmcnt(4)" ::: "memory");  // stores drained, prefetch flies
    } else {
      asm volatile("s_waitcnt vmcnt(0)" ::: "memory");
    }
    rawbar();
    if (tid == 0) coh_store_u32(&dflags[myidx], (unsigned)(u + 1));
    if (u + 1 < T_) {
      const unsigned own = (unsigned)(u + 1);
      if (grp == 0) {
        if (tid < 32) {
          while (coh_load_u32(&dflags[tid]) < own) __builtin_amdgcn_s_sleep(2);
        }
      } else {
        if (tid < 32) {
          while (coh_load_u32(&dflags[32 + tid]) < own) __builtin_amdgcn_s_sleep(2);
        } else if (tid < 64) {
          unsigned cap = (unsigned)((u + 3 > 256) ? 256 : (u + 3));
          while (coh_load_u32(&dflags[tid - 32]) < cap) __builtin_amdgcn_s_sleep(2);
        }
      }
      rawbar();
      __builtin_amdgcn_fence(__ATOMIC_ACQUIRE, "agent");  // invalidate L1/L2
    }
  }
}

// ---- LayerNorm + dense2(relu) + dense3; one block per batch row ----
__global__ __launch_bounds__(256) void final_k(
    const float* __restrict__ h2, const float* __restrict__ gamma, const float* __restrict__ beta,
    const float* __restrict__ W2, const float* __restrict__ b2,
    const float* __restrict__ W3, const float* __restrict__ b3, float* __restrict__ out)
{
  __shared__ float y[512];
  __shared__ float redS[4], redQ[4], redP[4];
  int b = blockIdx.x, tid = threadIdx.x;
  int wave = tid >> 6, lane = tid & 63;
  float v0 = h2[b * H_ + tid], v1 = h2[b * H_ + 256 + tid];
  float s = v0 + v1, q = v0 * v0 + v1 * v1;
#pragma unroll
  for (int o = 32; o; o >>= 1) { s += __shfl_down(s, o); q += __shfl_down(q, o); }
  if (lane == 0) { redS[wave] = s; redQ[wave] = q; }
  __syncthreads();
  float tot = redS[0] + redS[1] + redS[2] + redS[3];
  float totq = redQ[0] + redQ[1] + redQ[2] + redQ[3];
  float mu = tot * (1.f / 512.f);
  float var = totq * (1.f / 512.f) - mu * mu;
  float rs = rsqrtf(var + 1e-3f);
  y[tid]       = (v0 - mu) * rs * gamma[tid] + beta[tid];
  y[tid + 256] = (v1 - mu) * rs * gamma[tid + 256] + beta[tid + 256];
  __syncthreads();
  float acc = b2[tid];
  for (int k = 0; k < 512; k++) acc += y[k] * W2[k * 256 + tid];
  float pv = fmaxf(acc, 0.f) * W3[tid];
#pragma unroll
  for (int o = 32; o; o >>= 1) pv += __shfl_down(pv, o);
  if (lane == 0) redP[wave] = pv;
  __syncthreads();
  if (tid == 0) out[b] = redP[0] + redP[1] + redP[2] + redP[3] + b3[0];
}

extern "C" void kernel_launch(void* const* d_in, const int* in_sizes, int n_in,
                              void* d_out, int out_size, void* d_ws, size_t ws_size,
                              hipStream_t stream)
{
  (void)in_sizes; (void)n_in; (void)out_size; (void)ws_size;
  const float* x    = (const float*)d_in[0];
  const float* W1   = (const float*)d_in[1];
  const float* b1   = (const float*)d_in[2];
  const float* Wx1  = (const float*)d_in[3];
  const float* Wh1  = (const float*)d_in[4];
  const float* bl1  = (const float*)d_in[5];
  const float* Wx2  = (const float*)d_in[6];
  const float* Wh2  = (const float*)d_in[7];
  const float* bl2  = (const float*)d_in[8];
  const float* gam  = (const float*)d_in[9];
  const float* bet  = (const float*)d_in[10];
  const float* W2   = (const float*)d_in[11];
  const float* b2   = (const float*)d_in[12];
  const float* W3   = (const float*)d_in[13];
  const float* b3   = (const float*)d_in[14];

  char* p = (char*)d_ws;
  const size_t MB = 1024 * 1024;
  __hip_bfloat16* wx1t = (__hip_bfloat16*)(p + 0 * MB);
  __hip_bfloat16* wh1t = (__hip_bfloat16*)(p + 2 * MB);
  __hip_bfloat16* wx2t = (__hip_bfloat16*)(p + 4 * MB);
  __hip_bfloat16* wh2t = (__hip_bfloat16*)(p + 6 * MB);
  __hip_bfloat16* w1b  = (__hip_bfloat16*)(p + 8 * MB);
  __hip_bfloat16* h0   = (__hip_bfloat16*)(p + 9 * MB);   // 32 MB
  __hip_bfloat16* seq  = (__hip_bfloat16*)(p + 41 * MB);  // 32 MB
  char* st = p + 73 * MB;
  __hip_bfloat16* h1A = (__hip_bfloat16*)st;                       // 4x128KB
  __hip_bfloat16* h1B = h1A + B_ * H_;
  __hip_bfloat16* h2A = h1B + B_ * H_;
  __hip_bfloat16* h2B = h2A + B_ * H_;
  float* h2f = (float*)(st + 512 * 1024);                          // 256KB
  unsigned* flags = (unsigned*)(st + 512 * 1024 + 256 * 1024);     // 1KB used
  int nzero = (int)((512 * 1024 + 256 * 1024 + 4096) / 4);

  transpose_cast_k<<<dim3(32, 8, 4), 256, 0, stream>>>(Wx1, Wh1, Wx2, Wh2, wx1t);
  prep_misc_k<<<256, 256, 0, stream>>>(W1, w1b, (float*)st, nzero);
  dense1_k<<<1024, 512, 0, stream>>>(x, w1b, b1, h0);

  void* args[] = { (void*)&h0, (void*)&seq,
                   (void*)&wh1t, (void*)&wx1t, (void*)&bl1,
                   (void*)&wh2t, (void*)&wx2t, (void*)&bl2,
                   (void*)&h1A, (void*)&h1B, (void*)&h2A, (void*)&h2B,
                   (void*)&h2f, (void*)&flags };
  hipLaunchCooperativeKernel((void*)lstm_fused_k, dim3(256), dim3(256), args,
                             SMEM_TOTAL, stream);

  final_k<<<128, 256, 0, stream>>>(h2f, gam, bet, W2, b2, W3, b3, (float*)d_out);
}

// Round 11
// 1640.002 us; speedup vs baseline: 2.8505x; 1.8882x over previous
//
#include <hip/hip_runtime.h>
#include <hip/hip_bf16.h>
#include <math.h>

#define B_ 128
#define T_ 256
#define F_ 64
#define H_ 512
#define G4_ 2048

// dynamic LDS layout (bytes)
#define WH_OFF 0        // 4 waves x 16KB Wh fragments
#define WX_OFF 65536    // 4 waves x 16KB Wx fragments
#define ST_OFF 131072   // 16KB staging: 2 x 8KB ping-pong (g[4][32][17] overlays)
#define SMEM_TOTAL 147456

typedef __attribute__((ext_vector_type(8))) short bf16x8;
typedef __attribute__((ext_vector_type(4))) float f32x4;

__device__ __forceinline__ float sigmoidf_(float x) { return 1.f / (1.f + expf(-x)); }

__device__ __forceinline__ void coh_store_u32(unsigned* p, unsigned v) {
  __hip_atomic_store(p, v, __ATOMIC_RELAXED, __HIP_MEMORY_SCOPE_AGENT);
}
__device__ __forceinline__ unsigned coh_load_u32(const unsigned* p) {
  return __hip_atomic_load(p, __ATOMIC_RELAXED, __HIP_MEMORY_SCOPE_AGENT);
}
__device__ __forceinline__ void rawbar() { __builtin_amdgcn_s_barrier(); }

// async 16B/lane global->LDS copy; LDS dest = uniform base + lane*16 (HW rule)
__device__ __forceinline__ void async_ld16(const void* g, void* l) {
  __builtin_amdgcn_global_load_lds(
      (const __attribute__((address_space(1))) void*)g,
      (__attribute__((address_space(3))) void*)l, 16, 0, 0);
}
// device-coherent variant: aux = SC0|SC1 (1|16) -> bypass stale L1/L2, read
// the coherence point directly. Replaces the per-step cache-wide invalidate.
__device__ __forceinline__ void async_ld16c(const void* g, void* l) {
  __builtin_amdgcn_global_load_lds(
      (const __attribute__((address_space(1))) void*)g,
      (__attribute__((address_space(3))) void*)l, 16, 0, 17);
}

// ---- transpose+cast four [512,2048] fp32 weight mats -> [2048,512] bf16 ----
__global__ __launch_bounds__(256) void transpose_cast_k(
    const float* __restrict__ s0, const float* __restrict__ s1,
    const float* __restrict__ s2, const float* __restrict__ s3,
    __hip_bfloat16* __restrict__ dst)
{
  __shared__ float lds[64][65];
  const float* src = (blockIdx.z == 0) ? s0 : (blockIdx.z == 1) ? s1 : (blockIdx.z == 2) ? s2 : s3;
  __hip_bfloat16* d = dst + (size_t)blockIdx.z * (G4_ * H_);
  int n0 = blockIdx.x * 64, k0 = blockIdx.y * 64;
  int tx = threadIdx.x & 63, ty = threadIdx.x >> 6;
#pragma unroll
  for (int r = 0; r < 16; r++) { int k = r * 4 + ty; lds[k][tx] = src[(size_t)(k0 + k) * G4_ + n0 + tx]; }
  __syncthreads();
#pragma unroll
  for (int r = 0; r < 16; r++) { int n = r * 4 + ty; d[(size_t)(n0 + n) * H_ + k0 + tx] = __float2bfloat16(lds[tx][n]); }
}

// ---- cast W1 to bf16 + zero state buffers & barrier flags ----
__global__ void prep_misc_k(const float* __restrict__ w1, __hip_bfloat16* __restrict__ w1b,
                            float* __restrict__ zbase, int nzero)
{
  int i = blockIdx.x * blockDim.x + threadIdx.x;
  int stride = gridDim.x * blockDim.x;
  for (int k = i; k < F_ * H_; k += stride) w1b[k] = __float2bfloat16(w1[k]);
  for (int k = i; k < nzero; k += stride) zbase[k] = 0.f;
}

// ---- dense1 + spectral-norm row normalization; h0 out as bf16 [B*T, H] ----
__global__ __launch_bounds__(512) void dense1_k(
    const float* __restrict__ x, const __hip_bfloat16* __restrict__ w1b,
    const float* __restrict__ b1, __hip_bfloat16* __restrict__ h0)
{
  __shared__ float red[8];
  int j = threadIdx.x;
  int wave = j >> 6, lane = j & 63;
  float wcol[64];
#pragma unroll
  for (int k = 0; k < 64; k++) wcol[k] = __bfloat162float(w1b[k * H_ + j]);
  float bj = b1[j];
  for (int r = 0; r < 32; r++) {
    int row = blockIdx.x * 32 + r;
    const float* xr = x + (size_t)row * F_;
    float acc = bj;
#pragma unroll
    for (int k = 0; k < 64; k++) acc += xr[k] * wcol[k];
    float ss = acc * acc;
#pragma unroll
    for (int o = 32; o; o >>= 1) ss += __shfl_down(ss, o);
    if (lane == 0) red[wave] = ss;
    __syncthreads();
    float tot = red[0] + red[1] + red[2] + red[3] + red[4] + red[5] + red[6] + red[7];
    float sc = sqrtf(512.f) / fmaxf(sqrtf(tot), 1e-12f);
    h0[(size_t)row * H_ + j] = __float2bfloat16(acc * sc);
    __syncthreads();
  }
}

// ---- fused persistent LSTM1+LSTM2, decoupled producer/consumer ----
// 256 blocks (1/CU): grp0 = LSTM1 (free-running producer), grp1 = LSTM2
// (consumer, lag>=2). Per grp per batch-strip: 32 unit-blocks exchange h each
// step via flags + agent stores; weights LDS-resident.
// Round 11: NO per-step cache invalidate. r10 paid a full L1+L2 buffer_inv
// every step (wiping 36MB of cache to refresh ~64KB/block), making every
// post-barrier load an IF-latency miss incl. the STATIC h0 x-tiles. Now the
// genuinely-fresh data (hin both grps, seq for grp1) uses device-coherent
// global_load_lds (aux=SC0|SC1: bypasses stale L1/L2, reads coherence point),
// while grp0's h0 stays plain-cached -> L2 warm across all 256 steps.
__global__ __launch_bounds__(256) void lstm_fused_k(
    const __hip_bfloat16* __restrict__ h0,     // [B*T, H] dense1 output (LSTM1 x)
    __hip_bfloat16* __restrict__ seq,          // [B*T, H] LSTM1 out / LSTM2 x
    const __hip_bfloat16* __restrict__ wh1, const __hip_bfloat16* __restrict__ wx1,
    const float* __restrict__ bl1,
    const __hip_bfloat16* __restrict__ wh2, const __hip_bfloat16* __restrict__ wx2,
    const float* __restrict__ bl2,
    __hip_bfloat16* __restrict__ h1A, __hip_bfloat16* __restrict__ h1B,
    __hip_bfloat16* __restrict__ h2A, __hip_bfloat16* __restrict__ h2B,
    float* __restrict__ h2f,                   // [B, H] fp32 final h of LSTM2
    unsigned* flags)                           // 4 domains x 64 flags
{
  extern __shared__ char smem[];
  const int tid = threadIdx.x;
  const int wave = tid >> 6;
  const int lane = tid & 63;
  const int lr = lane & 15;   // m (A-rows) / n (B-cols) within 16-tile
  const int lk = lane >> 4;   // k-octet quad
  const int bid = blockIdx.x;
  const int grp = bid >> 7;
  const int lid = bid & 127;
  const int bb = lid & 3;     // batch strip (32 rows) == sync domain
  const int bu = lid >> 2;    // unit strip (16 cols), 0..31
  const int m0 = bb * 32;
  const int u0 = bu * 16;
  const int gcol = wave * H_ + u0 + lr;  // this lane's gate-column in [0,2048)

  const __hip_bfloat16* Wht = grp ? wh2 : wh1;
  const __hip_bfloat16* Wxt = grp ? wx2 : wx1;
  const __hip_bfloat16* xsrc = grp ? (const __hip_bfloat16*)seq : h0;
  const float* bias = grp ? bl2 : bl1;
  __hip_bfloat16* hb0 = grp ? h2A : h1A;
  __hip_bfloat16* hb1 = grp ? h2B : h1B;
  unsigned* dflags = flags + bb * 64;
  const int myidx = (grp << 5) | bu;

  char* whs = smem + WH_OFF + wave * 16384;
  char* wxs = smem + WX_OFF + wave * 16384;
  char* stg = smem + ST_OFF;             // 2 x 8KB ping-pong (g overlays)
  float* gld = (float*)(smem + ST_OFF);  // g[gate][m][u] as [4][32][17]

  const float bias0 = bias[gcol];
  const int m_e = tid >> 3;
  const int up_e = tid & 7;
  float2 creg = {0.f, 0.f};

  const __hip_bfloat16* hin = hb0;       // updated per step
  const bool xcoh = (grp == 1);          // seq needs coherency; h0 does not

  // issue one 8KB sub-round (this wave's 2 chunks) into buf
  auto sub_issue = [&](int type, int half, char* buf, int tx) {
    const __hip_bfloat16* base;
    if (type == 0)      base = hin  + (size_t)(m0 + lr) * H_ + lk * 8;
    else if (type == 1) base = hin  + (size_t)(m0 + 16 + lr) * H_ + lk * 8;
    else if (type == 2) base = xsrc + ((size_t)(m0 + lr) * T_ + tx) * H_ + lk * 8;
    else                base = xsrc + ((size_t)(m0 + 16 + lr) * T_ + tx) * H_ + lk * 8;
    const bool coh = (type < 2) || xcoh;
#pragma unroll
    for (int j = 0; j < 2; j++) {
      const int kc = half * 8 + wave * 2 + j;
      if (coh) async_ld16c(base + kc * 32, buf + (wave * 2 + j) * 1024);
      else     async_ld16 (base + kc * 32, buf + (wave * 2 + j) * 1024);
    }
  };

  f32x4 acc0, acc1;
  // compute one 8KB sub-round: 8 MFMAs from buf + LDS weights
  auto sub_comp = [&](int type, int half, const char* buf) {
    const char* wsl = (type < 2) ? whs : wxs;
    f32x4 a = (type & 1) ? acc1 : acc0;
#pragma unroll
    for (int j = 0; j < 8; j++) {
      const int kc = half * 8 + j;
      bf16x8 av = *(const bf16x8*)(buf + j * 1024 + lane * 16);
      bf16x8 bw = *(const bf16x8*)(wsl + kc * 1024 + lane * 16);
      a = __builtin_amdgcn_mfma_f32_16x16x32_bf16(av, bw, a, 0, 0, 0);
    }
    if (type & 1) acc1 = a; else acc0 = a;
  };

  // ---- stage this wave's weight slices into LDS, fragment order (once) ----
  {
    const __hip_bfloat16* hsrcw = Wht + (size_t)gcol * H_ + lk * 8;
    const __hip_bfloat16* xsrcw = Wxt + (size_t)gcol * H_ + lk * 8;
#pragma unroll
    for (int i = 0; i < 16; i++) {
      *(bf16x8*)(whs + i * 1024 + lane * 16) = *(const bf16x8*)(hsrcw + i * 32);
      *(bf16x8*)(wxs + i * 1024 + lane * 16) = *(const bf16x8*)(xsrcw + i * 32);
    }
  }
  __syncthreads();

  // grp1: wait until grp0 is 2 steps ahead (seq[0], seq[1] published)
  if (grp == 1) {
    if (tid < 32) {
      while (coh_load_u32(&dflags[tid]) < 2u) __builtin_amdgcn_s_sleep(2);
    }
    __syncthreads();
  }

  // initial x prefetch for step 0 (x-lo halves into bufA/bufB)
  sub_issue(2, 0, stg, 0);
  sub_issue(2, 1, stg + 8192, 0);

  // sub-round schedule: Xlo-a, Xlo-b, Hlo-a, Hlo-b, Hhi-a, Hhi-b, Xhi-a, Xhi-b
  const int t_[8]  = {2, 2, 0, 0, 1, 1, 3, 3};
  const int hh_[8] = {0, 1, 0, 1, 0, 1, 0, 1};

  for (int u = 0; u < T_; u++) {
    hin = (u & 1) ? hb1 : hb0;
    __hip_bfloat16* hout = (u & 1) ? hb0 : hb1;

    acc0 = (f32x4){0.f, 0.f, 0.f, 0.f};
    acc1 = (f32x4){0.f, 0.f, 0.f, 0.f};

    // pipelined load+MFMA: ping-pong 8KB sub-rounds
#pragma unroll
    for (int r = 0; r < 8; r++) {
      if (r == 7) asm volatile("s_waitcnt vmcnt(0)" ::: "memory");
      else        asm volatile("s_waitcnt vmcnt(2)" ::: "memory");
      rawbar();
      char* buf = stg + (r & 1) * 8192;
      sub_comp(t_[r], hh_[r], buf);
      rawbar();
      if (r + 2 < 8) sub_issue(t_[r + 2], hh_[r + 2], buf, u);
    }

    // stage pre-activation gates in LDS (overlays staging; safe post-rawbar)
#pragma unroll
    for (int r = 0; r < 4; r++) {
      // C/D layout: col = lane&15, row = (lane>>4)*4 + r
      gld[wave * 544 + (lk * 4 + r) * 17 + lr]      = acc0[r] + bias0;
      gld[wave * 544 + (16 + lk * 4 + r) * 17 + lr] = acc1[r] + bias0;
    }
    __syncthreads();

    // elementwise: thread handles (m_e, units 2*up_e, 2*up_e+1)
    {
      const int gbase0 = m_e * 17 + 2 * up_e;
      float i0 = sigmoidf_(gld[0 * 544 + gbase0]);
      float i1 = sigmoidf_(gld[0 * 544 + gbase0 + 1]);
      float f0 = sigmoidf_(gld[1 * 544 + gbase0]);
      float f1 = sigmoidf_(gld[1 * 544 + gbase0 + 1]);
      float cb0 = tanhf(gld[2 * 544 + gbase0]);
      float cb1 = tanhf(gld[2 * 544 + gbase0 + 1]);
      float o0 = sigmoidf_(gld[3 * 544 + gbase0]);
      float o1 = sigmoidf_(gld[3 * 544 + gbase0 + 1]);
      float cn0 = f0 * creg.x + i0 * cb0;
      float cn1 = f1 * creg.y + i1 * cb1;
      creg.x = cn0; creg.y = cn1;
      float hv0 = o0 * tanhf(cn0);
      float hv1 = o1 * tanhf(cn1);
      union { __hip_bfloat16 h[2]; unsigned u32; } pk;
      pk.h[0] = __float2bfloat16(hv0);
      pk.h[1] = __float2bfloat16(hv1);
      const int row = m0 + m_e;
      const int col = u0 + 2 * up_e;
      coh_store_u32((unsigned*)hout + (row * H_ + col) / 2, pk.u32);
      if (grp == 0) {
        coh_store_u32((unsigned*)seq + (((size_t)row * T_ + u) * H_ + col) / 2, pk.u32);
      } else if (u == T_ - 1) {
        float2* dst = (float2*)(h2f + row * H_ + col);
        float2 hv = {hv0, hv1};
        *dst = hv;   // plain: kernel-end flush covers final_k
      }
    }
    rawbar();   // all g-reads retired (values consumed) before prefetch clobbers

    // prefetch next step's x-lo pre-barrier (grp0: static h0 warm in L2;
    // grp1: seq[u+1], published since grp0 >= u+2 guaranteed at step entry)
    if (u + 1 < T_) {
      sub_issue(2, 0, stg, u + 1);
      sub_issue(2, 1, stg + 8192, u + 1);
      asm volatile("s_waitcnt vmcnt(4)" ::: "memory");  // stores drained, prefetch flies
    } else {
      asm volatile("s_waitcnt vmcnt(0)" ::: "memory");
    }
    rawbar();
    if (tid == 0) coh_store_u32(&dflags[myidx], (unsigned)(u + 1));
    if (u + 1 < T_) {
      const unsigned own = (unsigned)(u + 1);
      if (grp == 0) {
        if (tid < 32) {
          while (coh_load_u32(&dflags[tid]) < own) __builtin_amdgcn_s_sleep(2);
        }
      } else {
        if (tid < 32) {
          while (coh_load_u32(&dflags[32 + tid]) < own) __builtin_amdgcn_s_sleep(2);
        } else if (tid < 64) {
          unsigned cap = (unsigned)((u + 3 > 256) ? 256 : (u + 3));
          while (coh_load_u32(&dflags[tid - 32]) < cap) __builtin_amdgcn_s_sleep(2);
        }
      }
      rawbar();
    }
  }
}

// ---- LayerNorm + dense2(relu) + dense3; one block per batch row ----
__global__ __launch_bounds__(256) void final_k(
    const float* __restrict__ h2, const float* __restrict__ gamma, const float* __restrict__ beta,
    const float* __restrict__ W2, const float* __restrict__ b2,
    const float* __restrict__ W3, const float* __restrict__ b3, float* __restrict__ out)
{
  __shared__ float y[512];
  __shared__ float redS[4], redQ[4], redP[4];
  int b = blockIdx.x, tid = threadIdx.x;
  int wave = tid >> 6, lane = tid & 63;
  float v0 = h2[b * H_ + tid], v1 = h2[b * H_ + 256 + tid];
  float s = v0 + v1, q = v0 * v0 + v1 * v1;
#pragma unroll
  for (int o = 32; o; o >>= 1) { s += __shfl_down(s, o); q += __shfl_down(q, o); }
  if (lane == 0) { redS[wave] = s; redQ[wave] = q; }
  __syncthreads();
  float tot = redS[0] + redS[1] + redS[2] + redS[3];
  float totq = redQ[0] + redQ[1] + redQ[2] + redQ[3];
  float mu = tot * (1.f / 512.f);
  float var = totq * (1.f / 512.f) - mu * mu;
  float rs = rsqrtf(var + 1e-3f);
  y[tid]       = (v0 - mu) * rs * gamma[tid] + beta[tid];
  y[tid + 256] = (v1 - mu) * rs * gamma[tid + 256] + beta[tid + 256];
  __syncthreads();
  float acc = b2[tid];
  for (int k = 0; k < 512; k++) acc += y[k] * W2[k * 256 + tid];
  float pv = fmaxf(acc, 0.f) * W3[tid];
#pragma unroll
  for (int o = 32; o; o >>= 1) pv += __shfl_down(pv, o);
  if (lane == 0) redP[wave] = pv;
  __syncthreads();
  if (tid == 0) out[b] = redP[0] + redP[1] + redP[2] + redP[3] + b3[0];
}

extern "C" void kernel_launch(void* const* d_in, const int* in_sizes, int n_in,
                              void* d_out, int out_size, void* d_ws, size_t ws_size,
                              hipStream_t stream)
{
  (void)in_sizes; (void)n_in; (void)out_size; (void)ws_size;
  const float* x    = (const float*)d_in[0];
  const float* W1   = (const float*)d_in[1];
  const float* b1   = (const float*)d_in[2];
  const float* Wx1  = (const float*)d_in[3];
  const float* Wh1  = (const float*)d_in[4];
  const float* bl1  = (const float*)d_in[5];
  const float* Wx2  = (const float*)d_in[6];
  const float* Wh2  = (const float*)d_in[7];
  const float* bl2  = (const float*)d_in[8];
  const float* gam  = (const float*)d_in[9];
  const float* bet  = (const float*)d_in[10];
  const float* W2   = (const float*)d_in[11];
  const float* b2   = (const float*)d_in[12];
  const float* W3   = (const float*)d_in[13];
  const float* b3   = (const float*)d_in[14];

  char* p = (char*)d_ws;
  const size_t MB = 1024 * 1024;
  __hip_bfloat16* wx1t = (__hip_bfloat16*)(p + 0 * MB);
  __hip_bfloat16* wh1t = (__hip_bfloat16*)(p + 2 * MB);
  __hip_bfloat16* wx2t = (__hip_bfloat16*)(p + 4 * MB);
  __hip_bfloat16* wh2t = (__hip_bfloat16*)(p + 6 * MB);
  __hip_bfloat16* w1b  = (__hip_bfloat16*)(p + 8 * MB);
  __hip_bfloat16* h0   = (__hip_bfloat16*)(p + 9 * MB);   // 32 MB
  __hip_bfloat16* seq  = (__hip_bfloat16*)(p + 41 * MB);  // 32 MB
  char* st = p + 73 * MB;
  __hip_bfloat16* h1A = (__hip_bfloat16*)st;                       // 4x128KB
  __hip_bfloat16* h1B = h1A + B_ * H_;
  __hip_bfloat16* h2A = h1B + B_ * H_;
  __hip_bfloat16* h2B = h2A + B_ * H_;
  float* h2f = (float*)(st + 512 * 1024);                          // 256KB
  unsigned* flags = (unsigned*)(st + 512 * 1024 + 256 * 1024);     // 1KB used
  int nzero = (int)((512 * 1024 + 256 * 1024 + 4096) / 4);

  transpose_cast_k<<<dim3(32, 8, 4), 256, 0, stream>>>(Wx1, Wh1, Wx2, Wh2, wx1t);
  prep_misc_k<<<256, 256, 0, stream>>>(W1, w1b, (float*)st, nzero);
  dense1_k<<<1024, 512, 0, stream>>>(x, w1b, b1, h0);

  void* args[] = { (void*)&h0, (void*)&seq,
                   (void*)&wh1t, (void*)&wx1t, (void*)&bl1,
                   (void*)&wh2t, (void*)&wx2t, (void*)&bl2,
                   (void*)&h1A, (void*)&h1B, (void*)&h2A, (void*)&h2B,
                   (void*)&h2f, (void*)&flags };
  hipLaunchCooperativeKernel((void*)lstm_fused_k, dim3(256), dim3(256), args,
                             SMEM_TOTAL, stream);

  final_k<<<128, 256, 0, stream>>>(h2f, gam, bet, W2, b2, W3, b3, (float*)d_out);
}